// Round 5
// baseline (321.685 us; speedup 1.0000x reference)
//
#include <hip/hip_runtime.h>

// ChemResBlock: S=16, A=512, F=64, L=12, 3 layers x 2 convs (shared weights/layer).
// Re-associated: yT[s][o][k*12+l] = sum_f x[s,k,f] w[o,l,f]
//   out[s,a,o] = sum_{kl} connB[s,a,kl] * yT[s][o][kl] + bondW (+node), relu
// R5: k_yT fuses partial-reduce+epilogue+stageA (x never hits global);
//     stageB BK=64, K-split 8 -> 1024 blocks = 4/CU (32 waves/CU).

typedef __attribute__((ext_vector_type(8))) short bf16x8;
typedef __attribute__((ext_vector_type(4))) float f32x4;
typedef unsigned short u16;
typedef unsigned int u32;

__device__ __forceinline__ u16 f2bf(float f) {
  union { float f; u32 u; } x; x.f = f;
  u32 r = x.u + 0x7fffu + ((x.u >> 16) & 1u);   // RNE
  return (u16)(r >> 16);
}

__device__ __forceinline__ void gload16(const void* g, void* l) {
  __builtin_amdgcn_global_load_lds((const __attribute__((address_space(1))) u32*)g,
                                   (__attribute__((address_space(3))) u32*)l, 16, 0, 0);
}

// ---------- prep ----------

__global__ __launch_bounds__(256) void k_cast_bf16(const float* __restrict__ src,
                                                   u16* __restrict__ dst, unsigned n8) {
  const unsigned stride = gridDim.x * 256;
  for (unsigned j = blockIdx.x * 256 + threadIdx.x; j < n8; j += stride) {
    const float4* s4 = (const float4*)src;
    float4 a = s4[2 * (size_t)j], b = s4[2 * (size_t)j + 1];
    ushort4 lo, hi;
    lo.x = f2bf(a.x); lo.y = f2bf(a.y); lo.z = f2bf(a.z); lo.w = f2bf(a.w);
    hi.x = f2bf(b.x); hi.y = f2bf(b.y); hi.z = f2bf(b.z); hi.w = f2bf(b.w);
    ((ushort4*)dst)[2 * (size_t)j] = lo;
    ((ushort4*)dst)[2 * (size_t)j + 1] = hi;
  }
}

// filters (3,64,12,66) -> wA [i][(l*64+o)][f] bf16 (drop bond cols)
__global__ __launch_bounds__(256) void k_w_pack(const float* __restrict__ filters,
                                                u16* __restrict__ wA) {
  int tid = blockIdx.x * 256 + threadIdx.x;  // < 3*768*64 = 147456
  int i = tid / 49152;
  int rem = tid - i * 49152;
  int row = rem >> 6, f = rem & 63;          // row = l*64+o
  int l = row >> 6, o = row & 63;
  wA[tid] = f2bf(filters[((size_t)((i * 64 + o) * 12 + l)) * 66 + f]);
}

// bondW[i][(s*512+a)*64+o] = sum_{l,j} bond[s,a,l,j] * filters[i,o,l,64+j]
__global__ __launch_bounds__(192) void k_bondw(const float* __restrict__ bond,
                                               const float* __restrict__ filters,
                                               float* __restrict__ bondW) {
  int blk = blockIdx.x;                      // s*512 + a
  int t = threadIdx.x;                       // 192 = 3 filters x 64 o
  __shared__ float lb[24];
  if (t < 24) lb[t] = bond[(size_t)blk * 24 + t];
  __syncthreads();
  int i = t >> 6, o = t & 63;
  float acc = 0.f;
#pragma unroll
  for (int l = 0; l < 12; ++l) {
    const float* wr = filters + ((size_t)((i * 64 + o) * 12 + l)) * 66 + 64;
    acc += lb[l * 2 + 0] * wr[0] + lb[l * 2 + 1] * wr[1];
  }
  bondW[(size_t)i * 524288 + (size_t)blk * 64 + o] = acc;
}

// ---------- k_yT: x-rows (from node OR partial-reduce+epilogue) -> yT slice ----------
// Block (kt, s): 32 atom rows k0=kt*32. mode 0: x = node (cast only).
//                mode 1: x = relu(sum_q pOut[q] + bW (+node if addNode)).
// Then yT[s][o][(k0+k)*12+l] = sum_f x[k,f] wA[(l*64+o)][f] via MFMA.
__global__ __launch_bounds__(256) void k_yT(const float* __restrict__ node,
                                            const float* __restrict__ pOut,
                                            const float* __restrict__ bW,
                                            const u16* __restrict__ wA,
                                            u16* __restrict__ yT,
                                            int mode, int addNode) {
  const int s = blockIdx.y, k0 = blockIdx.x * 32;
  __shared__ u16 xld[32 * 64];               // bf16 x tile, 16B-slot XOR (row&7)
  __shared__ u16 Z[12 * 64 * 36];            // transpose buffer (55.3 KB)
  const int tid = threadIdx.x, lane = tid & 63, wid = tid >> 6;
  const int r = lane & 15, g = lane >> 4;

  {
    const int row = tid >> 3, f0 = (tid & 7) * 8;
    const size_t e = ((size_t)s * 512 + k0 + row) * 64 + f0;
    float v[8];
    if (mode == 0) {
      float4 a = *(const float4*)&node[e], b = *(const float4*)&node[e + 4];
      v[0]=a.x; v[1]=a.y; v[2]=a.z; v[3]=b.x==b.x?a.w:a.w;  // keep simple below
      v[3]=a.w; v[4]=b.x; v[5]=b.y; v[6]=b.z; v[7]=b.w;
    } else {
      float4 sa = {0,0,0,0}, sb = {0,0,0,0};
#pragma unroll
      for (int q = 0; q < 8; ++q) {
        float4 a = *(const float4*)&pOut[(size_t)q * 524288 + e];
        float4 b = *(const float4*)&pOut[(size_t)q * 524288 + e + 4];
        sa.x += a.x; sa.y += a.y; sa.z += a.z; sa.w += a.w;
        sb.x += b.x; sb.y += b.y; sb.z += b.z; sb.w += b.w;
      }
      float4 ba = *(const float4*)&bW[e], bb = *(const float4*)&bW[e + 4];
      sa.x += ba.x; sa.y += ba.y; sa.z += ba.z; sa.w += ba.w;
      sb.x += bb.x; sb.y += bb.y; sb.z += bb.z; sb.w += bb.w;
      if (addNode) {
        float4 na = *(const float4*)&node[e], nb = *(const float4*)&node[e + 4];
        sa.x += na.x; sa.y += na.y; sa.z += na.z; sa.w += na.w;
        sb.x += nb.x; sb.y += nb.y; sb.z += nb.z; sb.w += nb.w;
      }
      v[0]=fmaxf(sa.x,0.f); v[1]=fmaxf(sa.y,0.f); v[2]=fmaxf(sa.z,0.f); v[3]=fmaxf(sa.w,0.f);
      v[4]=fmaxf(sb.x,0.f); v[5]=fmaxf(sb.y,0.f); v[6]=fmaxf(sb.z,0.f); v[7]=fmaxf(sb.w,0.f);
    }
    ushort4 h0, h1;
    h0.x=f2bf(v[0]); h0.y=f2bf(v[1]); h0.z=f2bf(v[2]); h0.w=f2bf(v[3]);
    h1.x=f2bf(v[4]); h1.y=f2bf(v[5]); h1.z=f2bf(v[6]); h1.w=f2bf(v[7]);
    const int slot = (f0 >> 3) ^ (row & 7);
    *(ushort4*)&xld[row * 64 + slot * 8] = h0;
    *(ushort4*)&xld[row * 64 + slot * 8 + 4] = h1;
  }
  __syncthreads();

#pragma unroll
  for (int lw = 0; lw < 3; ++lw) {
    const int l = wid * 3 + lw;
    f32x4 acc[4][2] = {};                    // [ot][kt2]
#pragma unroll
    for (int ks = 0; ks < 2; ++ks) {
      bf16x8 bv[2];
#pragma unroll
      for (int kt2 = 0; kt2 < 2; ++kt2) {
        const int k = kt2 * 16 + r;
        bv[kt2] = *(const bf16x8*)&xld[k * 64 + (((ks * 4 + g) ^ (k & 7)) << 3)];
      }
#pragma unroll
      for (int ot = 0; ot < 4; ++ot) {
        bf16x8 av = *(const bf16x8*)&wA[(size_t)(l * 64 + ot * 16 + r) * 64 + ks * 32 + g * 8];
#pragma unroll
        for (int kt2 = 0; kt2 < 2; ++kt2)
          acc[ot][kt2] = __builtin_amdgcn_mfma_f32_16x16x32_bf16(av, bv[kt2], acc[ot][kt2], 0, 0, 0);
      }
    }
#pragma unroll
    for (int ot = 0; ot < 4; ++ot)
#pragma unroll
      for (int kt2 = 0; kt2 < 2; ++kt2)
#pragma unroll
        for (int r2 = 0; r2 < 4; ++r2) {
          int o = ot * 16 + g * 4 + r2, k = kt2 * 16 + r;
          Z[l * 2304 + o * 36 + k] = f2bf(acc[ot][kt2][r2]);
        }
  }
  __syncthreads();
  u16* yb = yT + (size_t)s * 393216;
#pragma unroll
  for (int it = 0; it < 8; ++it) {
    int idx = it * 256 + tid;                // 64 o x 32 k
    int o = idx >> 5, k = idx & 31;
    u16 v[12];
#pragma unroll
    for (int l = 0; l < 12; ++l) v[l] = Z[l * 2304 + o * 36 + k];
    ushort4* dst = (ushort4*)&yb[(size_t)o * 6144 + (size_t)(k0 + k) * 12];
    ushort4 w0, w1, w2;
    w0.x = v[0]; w0.y = v[1]; w0.z = v[2]; w0.w = v[3];
    w1.x = v[4]; w1.y = v[5]; w1.z = v[6]; w1.w = v[7];
    w2.x = v[8]; w2.y = v[9]; w2.z = v[10]; w2.w = v[11];
    dst[0] = w0; dst[1] = w1; dst[2] = w2;
  }
}

// ---------- stage B: partial[kq] = connB[.., kq*768:+768] . yT[.., kq*768:+768]
// 64x64 tile, BK=64, 12 steps, 8 waves, LDS 32 KB -> 4 blocks/CU.
__global__ __launch_bounds__(512) void k_stageB(const u16* __restrict__ connB,
                                                const u16* __restrict__ yT,
                                                float* __restrict__ pOut) {
  const int b = blockIdx.x;                  // 1024 blocks
  const int xcd = b & 7, rest = b >> 3;      // 128 per XCD
  const int s = xcd * 2 + (rest & 1);
  const int rest2 = rest >> 1;
  const int bx = rest2 & 7, kq = rest2 >> 3; // m-tile, k-eighth
  const int row0 = bx * 64;
  const int k0 = kq * 768;
  const u16* Ab = connB + (size_t)s * 3145728 + (size_t)row0 * 6144 + k0;
  const u16* Bb = yT + (size_t)s * 393216 + k0;
  __shared__ __align__(16) u16 lA0[64 * 64], lA1[64 * 64];
  __shared__ __align__(16) u16 lB0[64 * 64], lB1[64 * 64];
  const int tid = threadIdx.x, lane = tid & 63, wid = tid >> 6;
  const int r = lane & 15, g = lane >> 4;
  const int wr = wid & 3, wc = wid >> 2;

  const int isA = wid < 4;
  const int wseg = (isA ? wid : wid - 4) * 16;   // 16-row staging segment
  const u16* sbase = isA ? Ab : Bb;
  const int lrow = lane >> 3;                // row within 8-row instr group
  const int lslot = lane & 7;

  f32x4 acc[2] = {};

#define STAGE(ST, LA, LB)                                                        \
  {                                                                              \
    u16* lds = isA ? (LA) : (LB);                                                \
    _Pragma("unroll")                                                            \
    for (int h = 0; h < 2; ++h) {                                                \
      const int R0 = wseg + h * 8;                                               \
      const int row = R0 + lrow;                                                 \
      const int slot = lslot ^ (row & 7);                                        \
      gload16(sbase + (size_t)row * 6144 + (ST) * 64 + slot * 8, lds + R0 * 64); \
    }                                                                            \
  }

#define COMPUTE(LA, LB)                                                          \
  {                                                                              \
    const int arow = wr * 16 + r;                                                \
    _Pragma("unroll")                                                            \
    for (int ks = 0; ks < 2; ++ks) {                                             \
      bf16x8 av = *(const bf16x8*)&(LA)[arow * 64 + ((((ks << 2) + g) ^ (arow & 7)) << 3)]; \
      _Pragma("unroll")                                                          \
      for (int c = 0; c < 2; ++c) {                                              \
        const int col = wc * 32 + c * 16 + r;                                    \
        bf16x8 bv = *(const bf16x8*)&(LB)[col * 64 + ((((ks << 2) + g) ^ (col & 7)) << 3)]; \
        acc[c] = __builtin_amdgcn_mfma_f32_16x16x32_bf16(av, bv, acc[c], 0, 0, 0); \
      }                                                                          \
    }                                                                            \
  }

  STAGE(0, lA0, lB0);
  __syncthreads();
#pragma unroll
  for (int st = 0; st < 12; st += 2) {
    if (st + 1 < 12) STAGE(st + 1, lA1, lB1);
    COMPUTE(lA0, lB0);
    __syncthreads();
    if (st + 2 < 12) STAGE(st + 2, lA0, lB0);
    COMPUTE(lA1, lB1);
    __syncthreads();
  }
#undef STAGE
#undef COMPUTE
  float* po = pOut + (size_t)kq * 524288 + ((size_t)s * 512 + row0) * 64;
#pragma unroll
  for (int c = 0; c < 2; ++c)
#pragma unroll
    for (int r2 = 0; r2 < 4; ++r2) {
      int m = wr * 16 + g * 4 + r2;
      int o = wc * 32 + c * 16 + r;
      po[m * 64 + o] = acc[c][r2];
    }
}

// ---------- final conv epilogue: d_out = relu(sum_q p[q] + bW + node) f32 ----------
__global__ __launch_bounds__(256) void k_finalLast(const float* __restrict__ pOut,
                                                   const float* __restrict__ bW,
                                                   const float* __restrict__ node,
                                                   float* __restrict__ outF) {
  size_t e = ((size_t)blockIdx.x * 256 + threadIdx.x) * 4;   // < 524288
  float4 sv = {0, 0, 0, 0};
#pragma unroll
  for (int q = 0; q < 8; ++q) {
    float4 a = *(const float4*)&pOut[(size_t)q * 524288 + e];
    sv.x += a.x; sv.y += a.y; sv.z += a.z; sv.w += a.w;
  }
  float4 bw = *(const float4*)&bW[e];
  float4 nd = *(const float4*)&node[e];
  sv.x = fmaxf(sv.x + bw.x + nd.x, 0.f);
  sv.y = fmaxf(sv.y + bw.y + nd.y, 0.f);
  sv.z = fmaxf(sv.z + bw.z + nd.z, 0.f);
  sv.w = fmaxf(sv.w + bw.w + nd.w, 0.f);
  *(float4*)&outF[e] = sv;
}

// ---------- fallback (f32, correct, slow) if ws too small ----------
__global__ __launch_bounds__(256) void k_fb_conv(const float* __restrict__ x,
                                                 const float* __restrict__ conn,
                                                 const float* __restrict__ bond,
                                                 const float* __restrict__ filt,
                                                 const float* __restrict__ node,
                                                 float* __restrict__ out, int addNode) {
  const int s = blockIdx.y, a = blockIdx.x;
  const int t = threadIdx.x;
  const int f = t & 63, lg = t >> 6;
  __shared__ float ncv[12 * 64];
  __shared__ float red[4][64];
  const float* cb = conn + ((size_t)(s * 512 + a)) * 6144;
  const float* xb = x + (size_t)s * 32768;
  float a0 = 0.f, a1 = 0.f, a2 = 0.f;
  for (int k = 0; k < 512; ++k) {
    float xv = xb[k * 64 + f];
    const float* cr = cb + k * 12 + lg * 3;
    a0 += cr[0] * xv; a1 += cr[1] * xv; a2 += cr[2] * xv;
  }
  ncv[(lg * 3 + 0) * 64 + f] = a0;
  ncv[(lg * 3 + 1) * 64 + f] = a1;
  ncv[(lg * 3 + 2) * 64 + f] = a2;
  __syncthreads();
  float p = 0.f;
  for (int l = lg * 3; l < lg * 3 + 3; ++l) {
    const float* wr = filt + ((size_t)(f * 12 + l)) * 66;
    float q = 0.f;
    for (int f2 = 0; f2 < 64; ++f2) q += ncv[l * 64 + f2] * wr[f2];
    q += bond[((size_t)(s * 512 + a) * 12 + l) * 2 + 0] * wr[64];
    q += bond[((size_t)(s * 512 + a) * 12 + l) * 2 + 1] * wr[65];
    p += q;
  }
  red[lg][f] = p;
  __syncthreads();
  if (t < 64) {
    float v = red[0][t] + red[1][t] + red[2][t] + red[3][t];
    if (addNode) v += node[((size_t)(s * 512 + a)) * 64 + t];
    out[((size_t)(s * 512 + a)) * 64 + t] = fmaxf(v, 0.f);
  }
}

extern "C" void kernel_launch(void* const* d_in, const int* in_sizes, int n_in,
                              void* d_out, int out_size, void* d_ws, size_t ws_size,
                              hipStream_t stream) {
  (void)in_sizes; (void)n_in; (void)out_size;
  const float* node    = (const float*)d_in[0];
  const float* conn    = (const float*)d_in[1];
  const float* bond    = (const float*)d_in[2];
  const float* filters = (const float*)d_in[3];
  float* outF = (float*)d_out;

  const size_t OFF_CONNB = 0;           // 16*512*6144*2 = 100,663,296
  const size_t OFF_YT    = 100663296;   // 16*64*6144*2  =  12,582,912
  const size_t OFF_WA    = 113246208;   // 3*768*64*2    =     294,912
  const size_t OFF_BW    = 113541120;   // 3*16*512*64*4 =   6,291,456
  const size_t OFF_POUT  = 119832576;   // 8*16*512*64*4 =  16,777,216
  const size_t WS_NEED   = 136609792;

  if (ws_size >= WS_NEED) {
    unsigned char* ws = (unsigned char*)d_ws;
    u16* connB = (u16*)(ws + OFF_CONNB);
    u16* yT    = (u16*)(ws + OFF_YT);
    u16* wA    = (u16*)(ws + OFF_WA);
    float* bW  = (float*)(ws + OFF_BW);
    float* pO  = (float*)(ws + OFF_POUT);

    // conn: 50,331,648 elems -> n8 = 6,291,456
    k_cast_bf16<<<dim3(2048), dim3(256), 0, stream>>>(conn, connB, 6291456u);
    k_w_pack<<<dim3(576), dim3(256), 0, stream>>>(filters, wA);
    k_bondw<<<dim3(8192), dim3(192), 0, stream>>>(bond, filters, bW);

    // initial yT from node (mode 0), filter 0
    k_yT<<<dim3(16, 16), dim3(256), 0, stream>>>(node, pO, bW, wA, yT, 0, 0);
    for (int j = 0; j < 6; ++j) {
      k_stageB<<<dim3(1024), dim3(512), 0, stream>>>(connB, yT, pO);
      if (j < 5) {
        int inext = (j + 1) >> 1;            // filter for NEXT conv's yT
        int icur = j >> 1;                   // bias for THIS conv's epilogue
        k_yT<<<dim3(16, 16), dim3(256), 0, stream>>>(node, pO,
                                                     bW + (size_t)icur * 524288,
                                                     wA + (size_t)inext * 49152,
                                                     yT, 1, j & 1);
      } else {
        k_finalLast<<<dim3(512), dim3(256), 0, stream>>>(pO, bW + 2 * 524288, node, outF);
      }
    }
  } else {
    float* buf = (float*)d_ws;
    const float* xc = node;
    for (int j = 0; j < 6; ++j) {
      int i = j >> 1;
      float* dst = (j & 1) ? outF : buf;
      k_fb_conv<<<dim3(512, 16), dim3(256), 0, stream>>>(xc, conn, bond,
                                                         filters + (size_t)i * 50688,
                                                         node, dst, j & 1);
      xc = dst;
    }
  }
}